// Round 3
// baseline (358.963 us; speedup 1.0000x reference)
//
#include <hip/hip_runtime.h>
#include <hip/hip_bf16.h>
#include <stdint.h>

#define NEXP 64
#define TTOK 32768
#define HID  1024
#define IMID 512
#define CAP  1024

typedef __bf16 bf16x8 __attribute__((ext_vector_type(8)));
typedef float  f32x4  __attribute__((ext_vector_type(4)));

static __device__ __forceinline__ unsigned int f2bf_u(float f) {
    __hip_bfloat16 h = __float2bfloat16(f);
    return (unsigned int)*reinterpret_cast<unsigned short*>(&h);
}
static __device__ __forceinline__ unsigned int pack2(float lo, float hi) {
    return f2bf_u(lo) | (f2bf_u(hi) << 16);
}
static __device__ __forceinline__ unsigned short f2bf_s(float f) {
    __hip_bfloat16 h = __float2bfloat16(f);
    return *reinterpret_cast<unsigned short*>(&h);
}

static __device__ __forceinline__ void gload16(const void* g, void* l) {
    __builtin_amdgcn_global_load_lds(
        (const __attribute__((address_space(1))) unsigned int*)g,
        (__attribute__((address_space(3))) unsigned int*)l,
        16, 0, 0);
}

// ================= preprocessing: x fp32 [T,1024] -> bf16 =================
__global__ __launch_bounds__(256)
void cvt_x_k(const float* __restrict__ x, unsigned short* __restrict__ xbf) {
    size_t i = ((size_t)blockIdx.x * 256 + threadIdx.x) * 8;
    f32x4 a = *reinterpret_cast<const f32x4*>(x + i);
    f32x4 b = *reinterpret_cast<const f32x4*>(x + i + 4);
    uint4 o;
    o.x = pack2(a.x, a.y); o.y = pack2(a.z, a.w);
    o.z = pack2(b.x, b.y); o.w = pack2(b.z, b.w);
    *reinterpret_cast<uint4*>(xbf + i) = o;
}

// ================= GEMM1: xbf[cnt,1024] x w13(fp32, inline cvt) -> SwiGLU ->
//                   hbuf bf16 [T,512]
// Tile: BM=256, BN=128 (64 gate + 64 up cols, 16-col chunks interleaved),
// BK=64, 512 threads = 8 waves (4x2). B reg-staged transposed into LDS.
__global__ __launch_bounds__(512, 2)
void gemm1(const unsigned short* __restrict__ xbf,
           const int* __restrict__ tpe,
           const float* __restrict__ w13,
           unsigned short* __restrict__ hbuf) {
    const int nt = blockIdx.x;   // 0..7 : intermediate cols [nt*64, +64)
    const int mt = blockIdx.y;   // 0..3
    const int e  = blockIdx.z;

    int cnt = tpe[e]; if (cnt > CAP) cnt = CAP;
    const int m0 = mt * 256;
    if (m0 >= cnt) return;
    int start = 0;
    for (int i = 0; i < e; ++i) start += tpe[i];

    __shared__ alignas(16) unsigned short As[256 * 64];  // [m][k] linear, 128B rows
    __shared__ alignas(16) unsigned short Bs[128 * 64];  // [n'][k], XOR-swizzled

    const int t    = threadIdx.x;
    const int lane = t & 63;
    const int w    = t >> 6;               // 0..7
    const int wr   = w >> 1, wc = w & 1;   // 4 x 2 wave grid
    const int r    = lane & 15, q = lane >> 4;
    const int pr   = ((r & 3) << 2) | (r >> 2);   // perm(r), involution

    f32x4 acc[4][4];
    const f32x4 z4 = {0.f, 0.f, 0.f, 0.f};
    #pragma unroll
    for (int i = 0; i < 4; ++i)
        #pragma unroll
        for (int j = 0; j < 4; ++j) acc[i][j] = z4;

    // A staging (global_load_lds): row t>>3 (+64/pass), 16B chunk t&7
    const int skb  = (t & 7) * 16;
    const int srow = t >> 3;               // 0..63

    // B staging: slot s covers 4 fp32 cols; kb = 4-k group
    const int s    = t & 31;
    const int kb   = (t >> 5) << 2;        // 0..60
    const int isup = s >> 4;
    const int scol = (s & 15) << 2;        // 0..60 within 64-col range
    const float* bsrc = w13 + ((size_t)e << 20) + (size_t)(isup * 512 + nt * 64 + scol);

    int bofs[4];
    #pragma unroll
    for (int j = 0; j < 4; ++j) {
        int c = scol + j;                  // 0..63 intermediate col within block
        int chunk = c >> 4, within = c & 15;
        int np = chunk * 32 + isup * 16 + (((within & 3) << 2) | (within >> 2));
        bofs[j] = np * 128 + ((kb * 2) ^ ((np & 7) << 4));
    }

    const char* aP = (const char*)xbf;
    char* AsB = (char*)As;
    char* BsB = (char*)Bs;

    for (int kt = 0; kt < 16; ++kt) {
        __syncthreads();
        // ---- B loads (coalesced fp32 rows) ----
        const float* bk = bsrc + (size_t)(kt * 64 + kb) * 1024;
        f32x4 bv0 = *reinterpret_cast<const f32x4*>(bk);
        f32x4 bv1 = *reinterpret_cast<const f32x4*>(bk + 1024);
        f32x4 bv2 = *reinterpret_cast<const f32x4*>(bk + 2048);
        f32x4 bv3 = *reinterpret_cast<const f32x4*>(bk + 3072);
        // ---- A async stage ----
        #pragma unroll
        for (int i = 0; i < 4; ++i) {
            long grow = (long)start + m0 + srow + i * 64;
            if (grow > TTOK - 1) grow = TTOK - 1;
            gload16(aP + grow * 2048 + kt * 128 + skb, AsB + (srow + i * 64) * 128 + skb);
        }
        // ---- B cvt + transposed write ----
        #pragma unroll
        for (int j = 0; j < 4; ++j) {
            uint2 wv;
            wv.x = pack2(bv0[j], bv1[j]);
            wv.y = pack2(bv2[j], bv3[j]);
            *reinterpret_cast<uint2*>(BsB + bofs[j]) = wv;
        }
        __syncthreads();
        // ---- compute ----
        #pragma unroll
        for (int kk = 0; kk < 2; ++kk) {
            bf16x8 af[4], bf[4];
            #pragma unroll
            for (int fm = 0; fm < 4; ++fm) {
                int row = (wr << 6) + (fm << 4) + r;
                af[fm] = *reinterpret_cast<const bf16x8*>(AsB + row * 128 + kk * 64 + q * 16);
            }
            #pragma unroll
            for (int fn = 0; fn < 4; ++fn) {
                int row = (wc << 6) + (fn << 4) + r;
                bf[fn] = *reinterpret_cast<const bf16x8*>(
                    BsB + row * 128 + ((kk * 64 + q * 16) ^ ((row & 7) << 4)));
            }
            #pragma unroll
            for (int fm = 0; fm < 4; ++fm)
                #pragma unroll
                for (int fn = 0; fn < 4; ++fn)
                    acc[fm][fn] = __builtin_amdgcn_mfma_f32_16x16x32_bf16(af[fm], bf[fn], acc[fm][fn], 0, 0, 0);
        }
    }

    // ---- epilogue: SwiGLU (even fn = gate, odd fn = up, same chunk) ----
    #pragma unroll
    for (int fm = 0; fm < 4; ++fm) {
        int mb = m0 + (wr << 6) + (fm << 4) + (q << 2);
        #pragma unroll
        for (int fp = 0; fp < 2; ++fp) {
            f32x4 g = acc[fm][2 * fp];
            f32x4 u = acc[fm][2 * fp + 1];
            int c = ((nt << 2) + (wc << 1) + fp) * 16 + pr;
            #pragma unroll
            for (int v = 0; v < 4; ++v) {
                if (mb + v < cnt) {
                    float gv = g[v];
                    float sv = (gv / (1.f + __expf(-gv))) * u[v];
                    hbuf[(size_t)(start + mb + v) * IMID + c] = f2bf_s(sv);
                }
            }
        }
    }
}

// ================= GEMM2: hbuf[cnt,512] x w2(fp32, inline cvt) -> out fp32
// Tile: BM=256, BN=128, BK=64, 512 threads (4x2 waves).
__global__ __launch_bounds__(512, 2)
void gemm2(const unsigned short* __restrict__ hbuf,
           const int* __restrict__ tpe,
           const float* __restrict__ w2,
           float* __restrict__ out) {
    const int nt = blockIdx.x;   // 0..7
    const int mt = blockIdx.y;   // 0..3
    const int e  = blockIdx.z;

    int cnt = tpe[e]; if (cnt > CAP) cnt = CAP;
    const int m0 = mt * 256;
    if (m0 >= cnt) return;
    int start = 0;
    for (int i = 0; i < e; ++i) start += tpe[i];

    __shared__ alignas(16) unsigned short As[256 * 64];
    __shared__ alignas(16) unsigned short Bs[128 * 64];

    const int t    = threadIdx.x;
    const int lane = t & 63;
    const int w    = t >> 6;
    const int wr   = w >> 1, wc = w & 1;
    const int r    = lane & 15, q = lane >> 4;
    const int pr   = ((r & 3) << 2) | (r >> 2);

    f32x4 acc[4][4];
    const f32x4 z4 = {0.f, 0.f, 0.f, 0.f};
    #pragma unroll
    for (int i = 0; i < 4; ++i)
        #pragma unroll
        for (int j = 0; j < 4; ++j) acc[i][j] = z4;

    const int skb  = (t & 7) * 16;
    const int srow = t >> 3;

    const int s  = t & 31;
    const int kb = (t >> 5) << 2;
    const float* bsrc = w2 + (size_t)e * (IMID * HID) + (size_t)(nt * 128 + s * 4);

    int bofs[4];
    #pragma unroll
    for (int j = 0; j < 4; ++j) {
        int c = s * 4 + j;                 // 0..127
        int within = c & 15;
        int np = (c & 0x70) | (((within & 3) << 2) | (within >> 2));
        bofs[j] = np * 128 + ((kb * 2) ^ ((np & 7) << 4));
    }

    const char* aP = (const char*)hbuf;
    char* AsB = (char*)As;
    char* BsB = (char*)Bs;

    for (int kt = 0; kt < 8; ++kt) {
        __syncthreads();
        const float* bk = bsrc + (size_t)(kt * 64 + kb) * 1024;
        f32x4 bv0 = *reinterpret_cast<const f32x4*>(bk);
        f32x4 bv1 = *reinterpret_cast<const f32x4*>(bk + 1024);
        f32x4 bv2 = *reinterpret_cast<const f32x4*>(bk + 2048);
        f32x4 bv3 = *reinterpret_cast<const f32x4*>(bk + 3072);
        #pragma unroll
        for (int i = 0; i < 4; ++i) {
            long grow = (long)start + m0 + srow + i * 64;
            if (grow > TTOK - 1) grow = TTOK - 1;
            gload16(aP + grow * 1024 + kt * 128 + skb, AsB + (srow + i * 64) * 128 + skb);
        }
        #pragma unroll
        for (int j = 0; j < 4; ++j) {
            uint2 wv;
            wv.x = pack2(bv0[j], bv1[j]);
            wv.y = pack2(bv2[j], bv3[j]);
            *reinterpret_cast<uint2*>(BsB + bofs[j]) = wv;
        }
        __syncthreads();
        #pragma unroll
        for (int kk = 0; kk < 2; ++kk) {
            bf16x8 af[4], bf[4];
            #pragma unroll
            for (int fm = 0; fm < 4; ++fm) {
                int row = (wr << 6) + (fm << 4) + r;
                af[fm] = *reinterpret_cast<const bf16x8*>(AsB + row * 128 + kk * 64 + q * 16);
            }
            #pragma unroll
            for (int fn = 0; fn < 4; ++fn) {
                int row = (wc << 6) + (fn << 4) + r;
                bf[fn] = *reinterpret_cast<const bf16x8*>(
                    BsB + row * 128 + ((kk * 64 + q * 16) ^ ((row & 7) << 4)));
            }
            #pragma unroll
            for (int fm = 0; fm < 4; ++fm)
                #pragma unroll
                for (int fn = 0; fn < 4; ++fn)
                    acc[fm][fn] = __builtin_amdgcn_mfma_f32_16x16x32_bf16(af[fm], bf[fn], acc[fm][fn], 0, 0, 0);
        }
    }

    #pragma unroll
    for (int fm = 0; fm < 4; ++fm) {
        int mb = m0 + (wr << 6) + (fm << 4) + (q << 2);
        #pragma unroll
        for (int fn = 0; fn < 4; ++fn) {
            int ocol = (nt << 7) + (wc << 6) + (fn << 4) + pr;
            #pragma unroll
            for (int v = 0; v < 4; ++v) {
                if (mb + v < cnt)
                    out[(size_t)(start + mb + v) * HID + ocol] = acc[fm][fn][v];
            }
        }
    }
}

extern "C" void kernel_launch(void* const* d_in, const int* in_sizes, int n_in,
                              void* d_out, int out_size, void* d_ws, size_t ws_size,
                              hipStream_t stream) {
    const float* x   = (const float*)d_in[0];
    const int*   tpe = (const int*)d_in[1];
    const float* w13 = (const float*)d_in[2];
    const float* w2  = (const float*)d_in[3];
    float* out = (float*)d_out;

    char* ws = (char*)d_ws;
    unsigned short* xbf  = (unsigned short*)(ws);                        // 67 MB
    unsigned short* hbuf = (unsigned short*)(ws + (size_t)TTOK * HID * 2); // 33.5 MB

    cvt_x_k<<<dim3(16384, 1, 1), dim3(256, 1, 1), 0, stream>>>(x, xbf);
    gemm1<<<dim3(8, 4, NEXP), dim3(512, 1, 1), 0, stream>>>(xbf, tpe, w13, hbuf);
    gemm2<<<dim3(8, 4, NEXP), dim3(512, 1, 1), 0, stream>>>(hbuf, tpe, w2, out);
}

// Round 4
// 355.977 us; speedup vs baseline: 1.0084x; 1.0084x over previous
//
#include <hip/hip_runtime.h>
#include <hip/hip_bf16.h>
#include <stdint.h>

#define NEXP 64
#define TTOK 32768
#define HID  1024
#define IMID 512
#define CAP  1024

typedef __bf16 bf16x8 __attribute__((ext_vector_type(8)));
typedef float  f32x4  __attribute__((ext_vector_type(4)));

static __device__ __forceinline__ unsigned int f2bf_u(float f) {
    __hip_bfloat16 h = __float2bfloat16(f);
    return (unsigned int)*reinterpret_cast<unsigned short*>(&h);
}
static __device__ __forceinline__ unsigned int pack2(float lo, float hi) {
    return f2bf_u(lo) | (f2bf_u(hi) << 16);
}
static __device__ __forceinline__ unsigned short f2bf_s(float f) {
    __hip_bfloat16 h = __float2bfloat16(f);
    return *reinterpret_cast<unsigned short*>(&h);
}

static __device__ __forceinline__ void gload16(const void* g, void* l) {
    __builtin_amdgcn_global_load_lds(
        (const __attribute__((address_space(1))) unsigned int*)g,
        (__attribute__((address_space(3))) unsigned int*)l,
        16, 0, 0);
}

// ================= cvt_x: fp32 [T,1024] -> bf16 =================
__global__ __launch_bounds__(256)
void cvt_x_k(const float* __restrict__ x, unsigned short* __restrict__ xbf) {
    size_t i = ((size_t)blockIdx.x * 256 + threadIdx.x) * 8;
    f32x4 a = *reinterpret_cast<const f32x4*>(x + i);
    f32x4 b = *reinterpret_cast<const f32x4*>(x + i + 4);
    uint4 o;
    o.x = pack2(a.x, a.y); o.y = pack2(a.z, a.w);
    o.z = pack2(b.x, b.y); o.w = pack2(b.z, b.w);
    *reinterpret_cast<uint4*>(xbf + i) = o;
}

// ================= GEMM1: xbf[cnt,1024] x w13(fp32 direct) -> SwiGLU -> hbuf
// BM=128, BN=64 n'-rows (=32 intermediate cols: gate/up paired 16-granular),
// BK=64, 256 thr / 4 waves (2x2). Double-buffered LDS; B reg-prefetched
// (T14 issue-early/write-late), A via global_load_lds.
__global__ __launch_bounds__(256, 3)
void gemm1(const unsigned short* __restrict__ xbf,
           const int* __restrict__ tpe,
           const float* __restrict__ w13,
           unsigned short* __restrict__ hbuf) {
    const int nt = blockIdx.x;   // 0..15 : intermediate cols [nt*32, +32)
    const int mt = blockIdx.y;   // 0..7
    const int e  = blockIdx.z;

    int cnt = tpe[e]; if (cnt > CAP) cnt = CAP;
    const int m0 = mt * 128;
    if (m0 >= cnt) return;
    int start = 0;
    for (int i = 0; i < e; ++i) start += tpe[i];

    __shared__ alignas(16) char As[2][128 * 128];  // [m][64k] bf16, linear
    __shared__ alignas(16) char Bs[2][64 * 128];   // [n'][64k] bf16, XOR-swz

    const int t    = threadIdx.x;
    const int lane = t & 63;
    const int w    = t >> 6;
    const int wr   = w >> 1, wc = w & 1;
    const int r    = lane & 15, q = lane >> 4;

    f32x4 acc[4][2];
    const f32x4 z4 = {0.f, 0.f, 0.f, 0.f};
    #pragma unroll
    for (int i = 0; i < 4; ++i) { acc[i][0] = z4; acc[i][1] = z4; }

    // A staging geometry (R2-proven)
    const int skb  = (lane & 7) * 16;
    const int srow = w * 32 + (lane >> 3);
    const char* aP = (const char*)xbf;   // 2048B rows

    // B staging geometry: thread covers 4 cols x 4 k per kt
    const int c4 = t & 15;               // col group (4 cols)
    const int kg = t >> 4;               // k group (4 k-rows)
    const int cc0 = c4 * 4;              // local col 0..60 (<32 gate, >=32 up)
    const int gcol0 = nt * 32 + (cc0 & 31) + ((cc0 >> 5) << 9);
    const float* bP = w13 + ((size_t)e << 20) + gcol0;
    // transposed LDS rows for the 4 cols
    int brow[4];
    #pragma unroll
    for (int j = 0; j < 4; ++j) {
        int cc = cc0 + j;
        int cl = cc & 31;
        brow[j] = (cl >> 4) * 32 + ((cc >> 5) << 4) + (cl & 15);
    }

    #define STAGE_A(buf, kt)                                                    \
        {                                                                       \
            char* dst = As[buf] + w * 4096;                                     \
            _Pragma("unroll")                                                   \
            for (int i = 0; i < 4; ++i) {                                       \
                long grow = (long)start + m0 + srow + i * 8;                    \
                if (grow > TTOK - 1) grow = TTOK - 1;                           \
                gload16(aP + grow * 2048 + (kt) * 128 + skb, dst + i * 1024);   \
            }                                                                   \
        }

    #define LOAD_B(kt)                                                          \
        bv0 = *reinterpret_cast<const f32x4*>(bP + (size_t)((kt) * 64 + kg * 4 + 0) * 1024); \
        bv1 = *reinterpret_cast<const f32x4*>(bP + (size_t)((kt) * 64 + kg * 4 + 1) * 1024); \
        bv2 = *reinterpret_cast<const f32x4*>(bP + (size_t)((kt) * 64 + kg * 4 + 2) * 1024); \
        bv3 = *reinterpret_cast<const f32x4*>(bP + (size_t)((kt) * 64 + kg * 4 + 3) * 1024);

    #define WRITE_B(buf)                                                        \
        _Pragma("unroll")                                                       \
        for (int j = 0; j < 4; ++j) {                                           \
            uint2 wv;                                                           \
            wv.x = pack2(bv0[j], bv1[j]);                                       \
            wv.y = pack2(bv2[j], bv3[j]);                                       \
            *reinterpret_cast<uint2*>(Bs[buf] + brow[j] * 128 +                 \
                ((kg * 8) ^ ((brow[j] & 7) << 4))) = wv;                        \
        }

    f32x4 bv0, bv1, bv2, bv3;

    // prologue
    LOAD_B(0);
    STAGE_A(0, 0);
    WRITE_B(0);
    __syncthreads();

    for (int kt = 0; kt < 16; ++kt) {
        const int cur = kt & 1, nxt = cur ^ 1;
        if (kt + 1 < 16) {
            LOAD_B(kt + 1);
            STAGE_A(nxt, kt + 1);
        }
        // compute on cur
        #pragma unroll
        for (int kk = 0; kk < 2; ++kk) {
            bf16x8 af[4], bf[2];
            #pragma unroll
            for (int fm = 0; fm < 4; ++fm) {
                int row = (wr << 6) + (fm << 4) + r;
                af[fm] = *reinterpret_cast<const bf16x8*>(As[cur] + row * 128 + kk * 64 + q * 16);
            }
            #pragma unroll
            for (int fn = 0; fn < 2; ++fn) {
                int row = (wc << 5) + (fn << 4) + r;
                bf[fn] = *reinterpret_cast<const bf16x8*>(
                    Bs[cur] + row * 128 + ((kk * 64 + q * 16) ^ ((row & 7) << 4)));
            }
            #pragma unroll
            for (int fm = 0; fm < 4; ++fm)
                #pragma unroll
                for (int fn = 0; fn < 2; ++fn)
                    acc[fm][fn] = __builtin_amdgcn_mfma_f32_16x16x32_bf16(af[fm], bf[fn], acc[fm][fn], 0, 0, 0);
        }
        if (kt + 1 < 16) { WRITE_B(nxt); }
        __syncthreads();
    }
    #undef STAGE_A
    #undef LOAD_B
    #undef WRITE_B

    // epilogue: SwiGLU (fn0 = gate, fn1 = up, same intermediate col)
    #pragma unroll
    for (int fm = 0; fm < 4; ++fm) {
        int mb = m0 + (wr << 6) + (fm << 4) + (q << 2);
        f32x4 g = acc[fm][0];
        f32x4 u = acc[fm][1];
        int c = nt * 32 + wc * 16 + r;
        #pragma unroll
        for (int v = 0; v < 4; ++v) {
            if (mb + v < cnt) {
                float gv = g[v];
                float sv = (gv / (1.f + __expf(-gv))) * u[v];
                hbuf[(size_t)(start + mb + v) * IMID + c] = f2bf_s(sv);
            }
        }
    }
}

// ================= GEMM2: hbuf[cnt,512] x w2(fp32 direct) -> out fp32
// Same structure: BM=128, BN=64, BK=64, dbuf + T14.
__global__ __launch_bounds__(256, 3)
void gemm2(const unsigned short* __restrict__ hbuf,
           const int* __restrict__ tpe,
           const float* __restrict__ w2,
           float* __restrict__ out) {
    const int nt = blockIdx.x;   // 0..15 : out cols [nt*64, +64)
    const int mt = blockIdx.y;   // 0..7
    const int e  = blockIdx.z;

    int cnt = tpe[e]; if (cnt > CAP) cnt = CAP;
    const int m0 = mt * 128;
    if (m0 >= cnt) return;
    int start = 0;
    for (int i = 0; i < e; ++i) start += tpe[i];

    __shared__ alignas(16) char As[2][128 * 128];
    __shared__ alignas(16) char Bs[2][64 * 128];

    const int t    = threadIdx.x;
    const int lane = t & 63;
    const int w    = t >> 6;
    const int wr   = w >> 1, wc = w & 1;
    const int r    = lane & 15, q = lane >> 4;

    f32x4 acc[4][2];
    const f32x4 z4 = {0.f, 0.f, 0.f, 0.f};
    #pragma unroll
    for (int i = 0; i < 4; ++i) { acc[i][0] = z4; acc[i][1] = z4; }

    const int skb  = (lane & 7) * 16;
    const int srow = w * 32 + (lane >> 3);
    const char* aP = (const char*)hbuf;  // 1024B rows

    const int c4 = t & 15;
    const int kg = t >> 4;
    const int cc0 = c4 * 4;
    const float* bP = w2 + (size_t)e * (IMID * HID) + nt * 64 + cc0;

    #define STAGE_A(buf, kt)                                                    \
        {                                                                       \
            char* dst = As[buf] + w * 4096;                                     \
            _Pragma("unroll")                                                   \
            for (int i = 0; i < 4; ++i) {                                       \
                long grow = (long)start + m0 + srow + i * 8;                    \
                if (grow > TTOK - 1) grow = TTOK - 1;                           \
                gload16(aP + grow * 1024 + (kt) * 128 + skb, dst + i * 1024);   \
            }                                                                   \
        }

    #define LOAD_B(kt)                                                          \
        bv0 = *reinterpret_cast<const f32x4*>(bP + (size_t)((kt) * 64 + kg * 4 + 0) * 1024); \
        bv1 = *reinterpret_cast<const f32x4*>(bP + (size_t)((kt) * 64 + kg * 4 + 1) * 1024); \
        bv2 = *reinterpret_cast<const f32x4*>(bP + (size_t)((kt) * 64 + kg * 4 + 2) * 1024); \
        bv3 = *reinterpret_cast<const f32x4*>(bP + (size_t)((kt) * 64 + kg * 4 + 3) * 1024);

    #define WRITE_B(buf)                                                        \
        _Pragma("unroll")                                                       \
        for (int j = 0; j < 4; ++j) {                                           \
            int row = cc0 + j;                                                  \
            uint2 wv;                                                           \
            wv.x = pack2(bv0[j], bv1[j]);                                       \
            wv.y = pack2(bv2[j], bv3[j]);                                       \
            *reinterpret_cast<uint2*>(Bs[buf] + row * 128 +                     \
                ((kg * 8) ^ ((row & 7) << 4))) = wv;                            \
        }

    f32x4 bv0, bv1, bv2, bv3;

    LOAD_B(0);
    STAGE_A(0, 0);
    WRITE_B(0);
    __syncthreads();

    for (int kt = 0; kt < 8; ++kt) {
        const int cur = kt & 1, nxt = cur ^ 1;
        if (kt + 1 < 8) {
            LOAD_B(kt + 1);
            STAGE_A(nxt, kt + 1);
        }
        #pragma unroll
        for (int kk = 0; kk < 2; ++kk) {
            bf16x8 af[4], bf[2];
            #pragma unroll
            for (int fm = 0; fm < 4; ++fm) {
                int row = (wr << 6) + (fm << 4) + r;
                af[fm] = *reinterpret_cast<const bf16x8*>(As[cur] + row * 128 + kk * 64 + q * 16);
            }
            #pragma unroll
            for (int fn = 0; fn < 2; ++fn) {
                int row = (wc << 5) + (fn << 4) + r;
                bf[fn] = *reinterpret_cast<const bf16x8*>(
                    Bs[cur] + row * 128 + ((kk * 64 + q * 16) ^ ((row & 7) << 4)));
            }
            #pragma unroll
            for (int fm = 0; fm < 4; ++fm)
                #pragma unroll
                for (int fn = 0; fn < 2; ++fn)
                    acc[fm][fn] = __builtin_amdgcn_mfma_f32_16x16x32_bf16(af[fm], bf[fn], acc[fm][fn], 0, 0, 0);
        }
        if (kt + 1 < 8) { WRITE_B(nxt); }
        __syncthreads();
    }
    #undef STAGE_A
    #undef LOAD_B
    #undef WRITE_B

    #pragma unroll
    for (int fm = 0; fm < 4; ++fm) {
        int mb = m0 + (wr << 6) + (fm << 4) + (q << 2);
        #pragma unroll
        for (int fn = 0; fn < 2; ++fn) {
            int ocol = nt * 64 + wc * 32 + fn * 16 + r;
            #pragma unroll
            for (int v = 0; v < 4; ++v) {
                if (mb + v < cnt)
                    out[(size_t)(start + mb + v) * HID + ocol] = acc[fm][fn][v];
            }
        }
    }
}

extern "C" void kernel_launch(void* const* d_in, const int* in_sizes, int n_in,
                              void* d_out, int out_size, void* d_ws, size_t ws_size,
                              hipStream_t stream) {
    const float* x   = (const float*)d_in[0];
    const int*   tpe = (const int*)d_in[1];
    const float* w13 = (const float*)d_in[2];
    const float* w2  = (const float*)d_in[3];
    float* out = (float*)d_out;

    char* ws = (char*)d_ws;
    unsigned short* xbf  = (unsigned short*)(ws);                          // 67 MB
    unsigned short* hbuf = (unsigned short*)(ws + (size_t)TTOK * HID * 2); // 33.5 MB

    cvt_x_k<<<dim3(16384, 1, 1), dim3(256, 1, 1), 0, stream>>>(x, xbf);
    gemm1<<<dim3(16, 8, NEXP), dim3(256, 1, 1), 0, stream>>>(xbf, tpe, w13, hbuf);
    gemm2<<<dim3(16, 8, NEXP), dim3(256, 1, 1), 0, stream>>>(hbuf, tpe, w2, out);
}

// Round 5
// 340.785 us; speedup vs baseline: 1.0533x; 1.0446x over previous
//
#include <hip/hip_runtime.h>
#include <hip/hip_bf16.h>
#include <stdint.h>

#define NEXP 64
#define TTOK 32768
#define HID  1024
#define IMID 512
#define CAP  1024

typedef __bf16 bf16x8 __attribute__((ext_vector_type(8)));
typedef float  f32x4  __attribute__((ext_vector_type(4)));

static __device__ __forceinline__ unsigned int f2bf_u(float f) {
    __hip_bfloat16 h = __float2bfloat16(f);
    return (unsigned int)*reinterpret_cast<unsigned short*>(&h);
}
static __device__ __forceinline__ unsigned int pack2(float lo, float hi) {
    return f2bf_u(lo) | (f2bf_u(hi) << 16);
}
static __device__ __forceinline__ unsigned short f2bf_s(float f) {
    __hip_bfloat16 h = __float2bfloat16(f);
    return *reinterpret_cast<unsigned short*>(&h);
}

static __device__ __forceinline__ void gload16(const void* g, void* l) {
    __builtin_amdgcn_global_load_lds(
        (const __attribute__((address_space(1))) unsigned int*)g,
        (__attribute__((address_space(3))) unsigned int*)l,
        16, 0, 0);
}

struct BSet { f32x4 v0, v1, v2, v3; };

static __device__ __forceinline__ void load_bset(BSet& s, const float* bP, int ktar, int kg) {
    const float* p = bP + (size_t)(ktar * 64 + kg * 4) * 1024;
    s.v0 = *reinterpret_cast<const f32x4*>(p);
    s.v1 = *reinterpret_cast<const f32x4*>(p + 1024);
    s.v2 = *reinterpret_cast<const f32x4*>(p + 2048);
    s.v3 = *reinterpret_cast<const f32x4*>(p + 3072);
}

static __device__ __forceinline__ void write_bset(char* Bsbuf, const BSet& s,
                                                  const int brow[4], int kg) {
    #pragma unroll
    for (int j = 0; j < 4; ++j) {
        uint2 wv;
        wv.x = pack2(s.v0[j], s.v1[j]);
        wv.y = pack2(s.v2[j], s.v3[j]);
        *reinterpret_cast<uint2*>(Bsbuf + brow[j] * 128 +
            ((kg * 8) ^ ((brow[j] & 7) << 4))) = wv;
    }
}

// wave-parallel exclusive prefix: sum of tpe[i] for i < e  (all 64 lanes participate)
static __device__ __forceinline__ int expert_start(const int* tpe, int e, int lane) {
    int v = tpe[lane];
    int contrib = (lane < e) ? v : 0;
    #pragma unroll
    for (int off = 1; off < 64; off <<= 1)
        contrib += __shfl_xor(contrib, off, 64);
    return contrib;
}

// ================= cvt_x: fp32 [T,1024] -> bf16 =================
__global__ __launch_bounds__(256)
void cvt_x_k(const float* __restrict__ x, unsigned short* __restrict__ xbf) {
    size_t i = ((size_t)blockIdx.x * 256 + threadIdx.x) * 8;
    f32x4 a = *reinterpret_cast<const f32x4*>(x + i);
    f32x4 b = *reinterpret_cast<const f32x4*>(x + i + 4);
    uint4 o;
    o.x = pack2(a.x, a.y); o.y = pack2(a.z, a.w);
    o.z = pack2(b.x, b.y); o.w = pack2(b.z, b.w);
    *reinterpret_cast<uint4*>(xbf + i) = o;
}

// ================= GEMM1: xbf[cnt,1024] x w13(fp32 direct) -> SwiGLU -> hbuf
// BM=128, BN=64 n' (=32 icols, gate/up 16-paired), BK=64, 256 thr / 4 waves.
// A: gload_lds, pre-swizzled source, 3 LDS bufs (2-deep). B: reg 3-deep.
// Raw s_barrier + counted vmcnt.
__global__ __launch_bounds__(256, 2)
void gemm1(const unsigned short* __restrict__ xbf,
           const int* __restrict__ tpe,
           const float* __restrict__ w13,
           unsigned short* __restrict__ hbuf) {
    // XCD-chunk swizzle: consecutive works co-XCD; work = e*128 + nt*8 + mt
    const int bid  = blockIdx.x;
    const int work = (bid & 7) * 1024 + (bid >> 3);
    const int e  = work >> 7;
    const int nt = (work & 127) >> 3;
    const int mt = work & 7;

    const int t    = threadIdx.x;
    const int lane = t & 63;
    const int w    = t >> 6;

    int cnt = tpe[e]; if (cnt > CAP) cnt = CAP;
    const int m0 = mt * 128;
    if (m0 >= cnt) return;
    const int start = expert_start(tpe, e, lane);

    __shared__ alignas(16) char As[3 * 128 * 128];  // 48 KB
    __shared__ alignas(16) char Bs[2 * 64 * 128];   // 16 KB

    const int wr = w >> 1, wc = w & 1;
    const int r  = lane & 15, q = lane >> 4;

    f32x4 acc[4][2];
    const f32x4 z4 = {0.f, 0.f, 0.f, 0.f};
    #pragma unroll
    for (int i = 0; i < 4; ++i) { acc[i][0] = z4; acc[i][1] = z4; }

    // A staging: per-lane swizzled source chunk
    const int swb  = (((lane & 7) ^ (lane >> 3)) << 4);   // swizzled 16B chunk
    const long arow0 = (long)start + m0 + w * 32 + (lane >> 3);
    const char* aP = (const char*)xbf;                    // 2048 B rows

    // B: thread covers 4 cols (c4) x 4 k (kg)
    const int c4 = t & 15;
    const int kg = t >> 4;                                // 0..15
    const int colb = (c4 < 8) ? nt * 32 + c4 * 4
                              : 512 + nt * 32 + (c4 - 8) * 4;
    const float* bP = w13 + ((size_t)e << 20) + colb;
    int brow[4];
    #pragma unroll
    for (int j = 0; j < 4; ++j) {
        int cc = c4 * 4 + j;
        int cl = cc & 31;
        brow[j] = (cl >> 4) * 32 + ((cc >> 5) << 4) + (cl & 15);
    }

    #define STAGE_A1(kt)                                                        \
        {                                                                       \
            char* dst = As + ((kt) % 3) * 16384 + w * 4096;                     \
            _Pragma("unroll")                                                   \
            for (int i = 0; i < 4; ++i) {                                       \
                long grow = arow0 + i * 8;                                      \
                if (grow > TTOK - 1) grow = TTOK - 1;                           \
                gload16(aP + grow * 2048 + (kt) * 128 + swb, dst + i * 1024);   \
            }                                                                   \
        }

    const int NT = 16;
    BSet b0, b1, b2;

    // prologue
    load_bset(b0, bP, 0, kg);
    STAGE_A1(0);
    STAGE_A1(1);
    load_bset(b1, bP, 1, kg);
    load_bset(b2, bP, 2, kg);
    write_bset(Bs, b0, brow, kg);
    asm volatile("s_waitcnt vmcnt(12)" ::: "memory");
    asm volatile("s_waitcnt lgkmcnt(0)" ::: "memory");
    __builtin_amdgcn_s_barrier();

    #pragma unroll
    for (int kt = 0; kt < NT; ++kt) {
        const char* Acur = As + (kt % 3) * 16384;
        const char* Bcur = Bs + (kt & 1) * 8192;
        if (kt + 2 < NT) STAGE_A1(kt + 2);
        if (kt + 3 < NT) {
            BSet& ld = ((kt % 3) == 0) ? b0 : ((kt % 3) == 1) ? b1 : b2;
            load_bset(ld, bP, kt + 3, kg);
        }
        #pragma unroll
        for (int kk = 0; kk < 2; ++kk) {
            bf16x8 af[4], bf[2];
            #pragma unroll
            for (int fm = 0; fm < 4; ++fm) {
                int row = (wr << 6) + (fm << 4) + r;
                af[fm] = *reinterpret_cast<const bf16x8*>(
                    Acur + row * 128 + ((kk * 64 + q * 16) ^ ((row & 7) << 4)));
            }
            #pragma unroll
            for (int fn = 0; fn < 2; ++fn) {
                int row = (wc << 5) + (fn << 4) + r;
                bf[fn] = *reinterpret_cast<const bf16x8*>(
                    Bcur + row * 128 + ((kk * 64 + q * 16) ^ ((row & 7) << 4)));
            }
            #pragma unroll
            for (int fm = 0; fm < 4; ++fm)
                #pragma unroll
                for (int fn = 0; fn < 2; ++fn)
                    acc[fm][fn] = __builtin_amdgcn_mfma_f32_16x16x32_bf16(af[fm], bf[fn], acc[fm][fn], 0, 0, 0);
        }
        if (kt + 1 < NT) {
            BSet& wrs = (((kt + 1) % 3) == 0) ? b0 : (((kt + 1) % 3) == 1) ? b1 : b2;
            write_bset(Bs + ((kt + 1) & 1) * 8192, wrs, brow, kg);
        }
        if (kt + 3 < NT)      { asm volatile("s_waitcnt vmcnt(12)" ::: "memory"); }
        else if (kt + 2 < NT) { asm volatile("s_waitcnt vmcnt(8)"  ::: "memory"); }
        else                  { asm volatile("s_waitcnt vmcnt(0)"  ::: "memory"); }
        asm volatile("s_waitcnt lgkmcnt(0)" ::: "memory");
        __builtin_amdgcn_s_barrier();
    }
    #undef STAGE_A1

    // epilogue: SwiGLU (fn0 = gate, fn1 = up, same intermediate col)
    #pragma unroll
    for (int fm = 0; fm < 4; ++fm) {
        int mb = m0 + (wr << 6) + (fm << 4) + (q << 2);
        f32x4 g = acc[fm][0];
        f32x4 u = acc[fm][1];
        int c = nt * 32 + wc * 16 + r;
        #pragma unroll
        for (int v = 0; v < 4; ++v) {
            if (mb + v < cnt) {
                float gv = g[v];
                float sv = (gv / (1.f + __expf(-gv))) * u[v];
                hbuf[(size_t)(start + mb + v) * IMID + c] = f2bf_s(sv);
            }
        }
    }
}

// ================= GEMM2: hbuf[cnt,512] x w2(fp32 direct) -> out fp32
__global__ __launch_bounds__(256, 2)
void gemm2(const unsigned short* __restrict__ hbuf,
           const int* __restrict__ tpe,
           const float* __restrict__ w2,
           float* __restrict__ out) {
    const int bid  = blockIdx.x;
    const int work = (bid & 7) * 1024 + (bid >> 3);
    const int e  = work >> 7;
    const int nt = (work & 127) >> 3;
    const int mt = work & 7;

    const int t    = threadIdx.x;
    const int lane = t & 63;
    const int w    = t >> 6;

    int cnt = tpe[e]; if (cnt > CAP) cnt = CAP;
    const int m0 = mt * 128;
    if (m0 >= cnt) return;
    const int start = expert_start(tpe, e, lane);

    __shared__ alignas(16) char As[3 * 128 * 128];
    __shared__ alignas(16) char Bs[2 * 64 * 128];

    const int wr = w >> 1, wc = w & 1;
    const int r  = lane & 15, q = lane >> 4;

    f32x4 acc[4][2];
    const f32x4 z4 = {0.f, 0.f, 0.f, 0.f};
    #pragma unroll
    for (int i = 0; i < 4; ++i) { acc[i][0] = z4; acc[i][1] = z4; }

    const int swb  = (((lane & 7) ^ (lane >> 3)) << 4);
    const long arow0 = (long)start + m0 + w * 32 + (lane >> 3);
    const char* aP = (const char*)hbuf;                   // 1024 B rows

    const int c4 = t & 15;
    const int kg = t >> 4;
    const float* bP = w2 + (size_t)e * (IMID * HID) + nt * 64 + c4 * 4;
    int brow[4];
    #pragma unroll
    for (int j = 0; j < 4; ++j) brow[j] = c4 * 4 + j;

    #define STAGE_A2(kt)                                                        \
        {                                                                       \
            char* dst = As + ((kt) % 3) * 16384 + w * 4096;                     \
            _Pragma("unroll")                                                   \
            for (int i = 0; i < 4; ++i) {                                       \
                long grow = arow0 + i * 8;                                      \
                if (grow > TTOK - 1) grow = TTOK - 1;                           \
                gload16(aP + grow * 1024 + (kt) * 128 + swb, dst + i * 1024);   \
            }                                                                   \
        }

    const int NT = 8;
    BSet b0, b1, b2;

    load_bset(b0, bP, 0, kg);
    STAGE_A2(0);
    STAGE_A2(1);
    load_bset(b1, bP, 1, kg);
    load_bset(b2, bP, 2, kg);
    write_bset(Bs, b0, brow, kg);
    asm volatile("s_waitcnt vmcnt(12)" ::: "memory");
    asm volatile("s_waitcnt lgkmcnt(0)" ::: "memory");
    __builtin_amdgcn_s_barrier();

    #pragma unroll
    for (int kt = 0; kt < NT; ++kt) {
        const char* Acur = As + (kt % 3) * 16384;
        const char* Bcur = Bs + (kt & 1) * 8192;
        if (kt + 2 < NT) STAGE_A2(kt + 2);
        if (kt + 3 < NT) {
            BSet& ld = ((kt % 3) == 0) ? b0 : ((kt % 3) == 1) ? b1 : b2;
            load_bset(ld, bP, kt + 3, kg);
        }
        #pragma unroll
        for (int kk = 0; kk < 2; ++kk) {
            bf16x8 af[4], bf[2];
            #pragma unroll
            for (int fm = 0; fm < 4; ++fm) {
                int row = (wr << 6) + (fm << 4) + r;
                af[fm] = *reinterpret_cast<const bf16x8*>(
                    Acur + row * 128 + ((kk * 64 + q * 16) ^ ((row & 7) << 4)));
            }
            #pragma unroll
            for (int fn = 0; fn < 2; ++fn) {
                int row = (wc << 5) + (fn << 4) + r;
                bf[fn] = *reinterpret_cast<const bf16x8*>(
                    Bcur + row * 128 + ((kk * 64 + q * 16) ^ ((row & 7) << 4)));
            }
            #pragma unroll
            for (int fm = 0; fm < 4; ++fm)
                #pragma unroll
                for (int fn = 0; fn < 2; ++fn)
                    acc[fm][fn] = __builtin_amdgcn_mfma_f32_16x16x32_bf16(af[fm], bf[fn], acc[fm][fn], 0, 0, 0);
        }
        if (kt + 1 < NT) {
            BSet& wrs = (((kt + 1) % 3) == 0) ? b0 : (((kt + 1) % 3) == 1) ? b1 : b2;
            write_bset(Bs + ((kt + 1) & 1) * 8192, wrs, brow, kg);
        }
        if (kt + 3 < NT)      { asm volatile("s_waitcnt vmcnt(12)" ::: "memory"); }
        else if (kt + 2 < NT) { asm volatile("s_waitcnt vmcnt(8)"  ::: "memory"); }
        else                  { asm volatile("s_waitcnt vmcnt(0)"  ::: "memory"); }
        asm volatile("s_waitcnt lgkmcnt(0)" ::: "memory");
        __builtin_amdgcn_s_barrier();
    }
    #undef STAGE_A2

    #pragma unroll
    for (int fm = 0; fm < 4; ++fm) {
        int mb = m0 + (wr << 6) + (fm << 4) + (q << 2);
        #pragma unroll
        for (int fn = 0; fn < 2; ++fn) {
            int ocol = nt * 64 + wc * 32 + fn * 16 + r;
            #pragma unroll
            for (int v = 0; v < 4; ++v) {
                if (mb + v < cnt)
                    out[(size_t)(start + mb + v) * HID + ocol] = acc[fm][fn][v];
            }
        }
    }
}

extern "C" void kernel_launch(void* const* d_in, const int* in_sizes, int n_in,
                              void* d_out, int out_size, void* d_ws, size_t ws_size,
                              hipStream_t stream) {
    const float* x   = (const float*)d_in[0];
    const int*   tpe = (const int*)d_in[1];
    const float* w13 = (const float*)d_in[2];
    const float* w2  = (const float*)d_in[3];
    float* out = (float*)d_out;

    char* ws = (char*)d_ws;
    unsigned short* xbf  = (unsigned short*)(ws);                          // 67 MB
    unsigned short* hbuf = (unsigned short*)(ws + (size_t)TTOK * HID * 2); // 33.5 MB

    cvt_x_k<<<dim3(16384, 1, 1), dim3(256, 1, 1), 0, stream>>>(x, xbf);
    gemm1<<<dim3(8192, 1, 1), dim3(256, 1, 1), 0, stream>>>(xbf, tpe, w13, hbuf);
    gemm2<<<dim3(8192, 1, 1), dim3(256, 1, 1), 0, stream>>>(hbuf, tpe, w2, out);
}

// Round 7
// 305.939 us; speedup vs baseline: 1.1733x; 1.1139x over previous
//
#include <hip/hip_runtime.h>
#include <hip/hip_bf16.h>
#include <stdint.h>

#define NEXP 64
#define TTOK 32768
#define HID  1024
#define IMID 512
#define CAP  1024

typedef __bf16 bf16x8 __attribute__((ext_vector_type(8)));
typedef float  f32x4  __attribute__((ext_vector_type(4)));

static __device__ __forceinline__ unsigned int f2bf_u(float f) {
    __hip_bfloat16 h = __float2bfloat16(f);
    return (unsigned int)*reinterpret_cast<unsigned short*>(&h);
}
static __device__ __forceinline__ unsigned int pack2(float lo, float hi) {
    return f2bf_u(lo) | (f2bf_u(hi) << 16);
}
static __device__ __forceinline__ unsigned short f2bf_s(float f) {
    __hip_bfloat16 h = __float2bfloat16(f);
    return *reinterpret_cast<unsigned short*>(&h);
}

static __device__ __forceinline__ void gload16(const void* g, void* l) {
    __builtin_amdgcn_global_load_lds(
        (const __attribute__((address_space(1))) unsigned int*)g,
        (__attribute__((address_space(3))) unsigned int*)l,
        16, 0, 0);
}

// wave-parallel exclusive prefix: sum of tpe[i] for i < e
static __device__ __forceinline__ int expert_start(const int* tpe, int e, int lane) {
    int v = tpe[lane];
    int contrib = (lane < e) ? v : 0;
    #pragma unroll
    for (int off = 1; off < 64; off <<= 1)
        contrib += __shfl_xor(contrib, off, 64);
    return contrib;
}

// ================= cvt_x: fp32 [T,1024] -> bf16 =================
__global__ __launch_bounds__(256)
void cvt_x_k(const float* __restrict__ x, unsigned short* __restrict__ xbf) {
    size_t i = ((size_t)blockIdx.x * 256 + threadIdx.x) * 8;
    f32x4 a = *reinterpret_cast<const f32x4*>(x + i);
    f32x4 b = *reinterpret_cast<const f32x4*>(x + i + 4);
    uint4 o;
    o.x = pack2(a.x, a.y); o.y = pack2(a.z, a.w);
    o.z = pack2(b.x, b.y); o.w = pack2(b.z, b.w);
    *reinterpret_cast<uint4*>(xbf + i) = o;
}

// ================= cvt_w13: fp32 [e][1024k][1024n] -> bf16 [e][np][1024k]
// np pairing (32-col granular): src col n -> icol=n&511, isup=n>>9,
// np = (icol>>5)*64 + isup*32 + (icol&31)
__global__ __launch_bounds__(256)
void cvt_w13_k(const float* __restrict__ src_base, unsigned short* __restrict__ dst_base) {
    const int n0 = blockIdx.x * 64, k0 = blockIdx.y * 64, e = blockIdx.z;
    __shared__ unsigned short Tl[64][72];
    const int t = threadIdx.x;
    const int kl = t >> 4, nl = (t & 15) * 4;
    const float* src = src_base + ((size_t)e << 20) + (size_t)k0 * 1024 + n0;
    #pragma unroll
    for (int p = 0; p < 4; ++p) {
        int k = kl + p * 16;
        f32x4 v = *reinterpret_cast<const f32x4*>(src + (size_t)k * 1024 + nl);
        uint2 wv; wv.x = pack2(v.x, v.y); wv.y = pack2(v.z, v.w);
        *reinterpret_cast<uint2*>(&Tl[k][nl]) = wv;
    }
    __syncthreads();
    const int nloc = t >> 2, kc = (t & 3) * 16;
    const int n = n0 + nloc;
    const int icol = n & 511, isup = n >> 9;
    const int np = (icol >> 5) * 64 + isup * 32 + (icol & 31);
    unsigned int v32[8];
    #pragma unroll
    for (int j = 0; j < 8; ++j)
        v32[j] = (unsigned int)Tl[kc + 2 * j][nloc] |
                 ((unsigned int)Tl[kc + 2 * j + 1][nloc] << 16);
    unsigned short* dst = dst_base + ((size_t)e << 20) + (size_t)np * 1024 + k0 + kc;
    uint4 o0 = {v32[0], v32[1], v32[2], v32[3]};
    uint4 o1 = {v32[4], v32[5], v32[6], v32[7]};
    *reinterpret_cast<uint4*>(dst)     = o0;
    *reinterpret_cast<uint4*>(dst + 8) = o1;
}

// one 64x64 transpose-convert tile of w2: fp32 [e][512k][1024n] -> bf16 [e][n][512k]
static __device__ __forceinline__ void w2_tile_cvt(const float* __restrict__ w2,
                                                   unsigned short* __restrict__ w2p,
                                                   int tile, int t, char* lds) {
    const int e  = tile >> 7;
    const int k0 = ((tile >> 4) & 7) * 64;
    const int n0 = (tile & 15) * 64;
    unsigned short (*Tl)[72] = reinterpret_cast<unsigned short(*)[72]>(lds);  // 9216 B
    const int kl = t >> 4, nl = (t & 15) * 4;
    const float* src = w2 + (size_t)e * (IMID * HID) + (size_t)k0 * 1024 + n0;
    #pragma unroll
    for (int p = 0; p < 4; ++p) {
        int k = kl + p * 16;
        f32x4 v = *reinterpret_cast<const f32x4*>(src + (size_t)k * 1024 + nl);
        uint2 wv; wv.x = pack2(v.x, v.y); wv.y = pack2(v.z, v.w);
        *reinterpret_cast<uint2*>(&Tl[k][nl]) = wv;
    }
    __syncthreads();
    const int nloc = t >> 2, kc = (t & 3) * 16;
    unsigned int v32[8];
    #pragma unroll
    for (int j = 0; j < 8; ++j)
        v32[j] = (unsigned int)Tl[kc + 2 * j][nloc] |
                 ((unsigned int)Tl[kc + 2 * j + 1][nloc] << 16);
    unsigned short* dst = w2p + (size_t)e * (HID * IMID) + (size_t)(n0 + nloc) * IMID + k0 + kc;
    uint4 o0 = {v32[0], v32[1], v32[2], v32[3]};
    uint4 o1 = {v32[4], v32[5], v32[6], v32[7]};
    *reinterpret_cast<uint4*>(dst)     = o0;
    *reinterpret_cast<uint4*>(dst + 8) = o1;
}

// ================= GEMM1: xbf[cnt,1024] x w13p -> SwiGLU -> hbuf bf16 [T,512]
// 128x128 tile, BK=64, 4 waves (2x2), all staging via global_load_lds with
// both-sides XOR swizzle. Tail: each block converts 2 w2 tiles.
__global__ __launch_bounds__(256, 3)
void gemm1(const unsigned short* __restrict__ xbf,
           const int* __restrict__ tpe,
           const unsigned short* __restrict__ w13p,
           unsigned short* __restrict__ hbuf,
           const float* __restrict__ w2,
           unsigned short* __restrict__ w2p) {
    __shared__ alignas(16) char lds[32768];
    const int bid  = blockIdx.x;                 // 4096 blocks
    const int work = (bid & 7) * 512 + (bid >> 3);
    const int e  = work >> 6;                    // 0..63
    const int nt = (work >> 3) & 7;              // 0..7 : 128 n'-rows = 64 icols
    const int mt = work & 7;                     // 0..7

    const int t = threadIdx.x, lane = t & 63, w = t >> 6;
    int cnt = tpe[e]; if (cnt > CAP) cnt = CAP;
    const int m0 = mt * 128;
    const int start = expert_start(tpe, e, lane);

    if (m0 < cnt) {
        char* As = lds;            // [128m][64k] bf16, source-swizzled
        char* Bs = lds + 16384;    // [128n'][64k] bf16, source-swizzled
        const int wr = w >> 1, wc = w & 1;
        const int r = lane & 15, q = lane >> 4;

        f32x4 acc[4][4];
        const f32x4 z4 = {0.f, 0.f, 0.f, 0.f};
        #pragma unroll
        for (int i = 0; i < 4; ++i)
            #pragma unroll
            for (int j = 0; j < 4; ++j) acc[i][j] = z4;

        const int swb = ((lane & 7) ^ (lane >> 3)) << 4;
        const char* aP = (const char*)xbf;   // 2048 B rows
        const char* bP = (const char*)w13p + ((size_t)e << 21) + (size_t)(nt * 128) * 2048;

        for (int kt = 0; kt < 16; ++kt) {
            __syncthreads();
            const int kb = kt * 128;
            #pragma unroll
            for (int i = 0; i < 4; ++i) {
                const int srow = w * 32 + i * 8 + (lane >> 3);
                long ar = (long)start + m0 + srow;
                if (ar > TTOK - 1) ar = TTOK - 1;
                gload16(aP + ar * 2048 + kb + swb, As + w * 4096 + i * 1024);
                gload16(bP + (size_t)srow * 2048 + kb + swb, Bs + w * 4096 + i * 1024);
            }
            __syncthreads();
            #pragma unroll
            for (int kk = 0; kk < 2; ++kk) {
                bf16x8 af[4], bf[4];
                #pragma unroll
                for (int fm = 0; fm < 4; ++fm) {
                    int row = (wr << 6) + (fm << 4) + r;
                    af[fm] = *reinterpret_cast<const bf16x8*>(
                        As + row * 128 + ((kk * 64 + q * 16) ^ ((row & 7) << 4)));
                }
                #pragma unroll
                for (int fn = 0; fn < 4; ++fn) {
                    int row = (wc << 6) + (fn << 4) + r;
                    bf[fn] = *reinterpret_cast<const bf16x8*>(
                        Bs + row * 128 + ((kk * 64 + q * 16) ^ ((row & 7) << 4)));
                }
                #pragma unroll
                for (int fm = 0; fm < 4; ++fm)
                    #pragma unroll
                    for (int fn = 0; fn < 4; ++fn)
                        acc[fm][fn] = __builtin_amdgcn_mfma_f32_16x16x32_bf16(
                            af[fm], bf[fn], acc[fm][fn], 0, 0, 0);
            }
        }

        // SwiGLU: n' = nt*128 + wc*64 + fn*16 + r; fn<2 = gate, fn>=2 = up
        #pragma unroll
        for (int fm = 0; fm < 4; ++fm) {
            int mb = m0 + (wr << 6) + (fm << 4) + (q << 2);
            #pragma unroll
            for (int fp = 0; fp < 2; ++fp) {
                f32x4 g = acc[fm][fp];
                f32x4 u = acc[fm][fp + 2];
                int icol = (nt * 2 + wc) * 32 + fp * 16 + r;
                #pragma unroll
                for (int v = 0; v < 4; ++v) {
                    if (mb + v < cnt) {
                        float gv = g[v];
                        float sv = (gv / (1.f + __expf(-gv))) * u[v];
                        hbuf[(size_t)(start + mb + v) * IMID + icol] = f2bf_s(sv);
                    }
                }
            }
        }
    }

    // ---- tail: convert 2 w2 tiles (8192 tiles / 4096 blocks) ----
    __syncthreads();
    #pragma unroll 1
    for (int j = 0; j < 2; ++j) {
        w2_tile_cvt(w2, w2p, bid * 2 + j, t, lds);
        __syncthreads();
    }
}

// ================= GEMM2: hbuf[cnt,512] x w2p -> out fp32 [T,1024]
__global__ __launch_bounds__(256, 3)
void gemm2(const unsigned short* __restrict__ hbuf,
           const int* __restrict__ tpe,
           const unsigned short* __restrict__ w2p,
           float* __restrict__ out) {
    __shared__ alignas(16) char lds[32768];
    const int bid  = blockIdx.x;                 // 4096 blocks
    const int work = (bid & 7) * 512 + (bid >> 3);
    const int e  = work >> 6;
    const int nt = (work >> 3) & 7;              // out cols [nt*128, +128)
    const int mt = work & 7;

    const int t = threadIdx.x, lane = t & 63, w = t >> 6;
    int cnt = tpe[e]; if (cnt > CAP) cnt = CAP;
    const int m0 = mt * 128;
    if (m0 >= cnt) return;
    const int start = expert_start(tpe, e, lane);

    char* As = lds;
    char* Bs = lds + 16384;
    const int wr = w >> 1, wc = w & 1;
    const int r = lane & 15, q = lane >> 4;

    f32x4 acc[4][4];
    const f32x4 z4 = {0.f, 0.f, 0.f, 0.f};
    #pragma unroll
    for (int i = 0; i < 4; ++i)
        #pragma unroll
        for (int j = 0; j < 4; ++j) acc[i][j] = z4;

    const int swb = ((lane & 7) ^ (lane >> 3)) << 4;
    const char* aP = (const char*)hbuf;   // 1024 B rows
    const char* bP = (const char*)w2p + ((size_t)e << 20) + (size_t)(nt * 128) * 1024;

    for (int kt = 0; kt < 8; ++kt) {
        __syncthreads();
        const int kb = kt * 128;
        #pragma unroll
        for (int i = 0; i < 4; ++i) {
            const int srow = w * 32 + i * 8 + (lane >> 3);
            long ar = (long)start + m0 + srow;
            if (ar > TTOK - 1) ar = TTOK - 1;
            gload16(aP + ar * 1024 + kb + swb, As + w * 4096 + i * 1024);
            gload16(bP + (size_t)srow * 1024 + kb + swb, Bs + w * 4096 + i * 1024);
        }
        __syncthreads();
        #pragma unroll
        for (int kk = 0; kk < 2; ++kk) {
            bf16x8 af[4], bf[4];
            #pragma unroll
            for (int fm = 0; fm < 4; ++fm) {
                int row = (wr << 6) + (fm << 4) + r;
                af[fm] = *reinterpret_cast<const bf16x8*>(
                    As + row * 128 + ((kk * 64 + q * 16) ^ ((row & 7) << 4)));
            }
            #pragma unroll
            for (int fn = 0; fn < 4; ++fn) {
                int row = (wc << 6) + (fn << 4) + r;
                bf[fn] = *reinterpret_cast<const bf16x8*>(
                    Bs + row * 128 + ((kk * 64 + q * 16) ^ ((row & 7) << 4)));
            }
            #pragma unroll
            for (int fm = 0; fm < 4; ++fm)
                #pragma unroll
                for (int fn = 0; fn < 4; ++fn)
                    acc[fm][fn] = __builtin_amdgcn_mfma_f32_16x16x32_bf16(
                        af[fm], bf[fn], acc[fm][fn], 0, 0, 0);
        }
    }

    #pragma unroll
    for (int fm = 0; fm < 4; ++fm) {
        int mb = m0 + (wr << 6) + (fm << 4) + (q << 2);
        #pragma unroll
        for (int fn = 0; fn < 4; ++fn) {
            int ocol = (nt << 7) + (wc << 6) + (fn << 4) + r;
            #pragma unroll
            for (int v = 0; v < 4; ++v) {
                if (mb + v < cnt)
                    out[(size_t)(start + mb + v) * HID + ocol] = acc[fm][fn][v];
            }
        }
    }
}

extern "C" void kernel_launch(void* const* d_in, const int* in_sizes, int n_in,
                              void* d_out, int out_size, void* d_ws, size_t ws_size,
                              hipStream_t stream) {
    const float* x   = (const float*)d_in[0];
    const int*   tpe = (const int*)d_in[1];
    const float* w13 = (const float*)d_in[2];
    const float* w2  = (const float*)d_in[3];
    float* out = (float*)d_out;

    char* ws = (char*)d_ws;
    unsigned short* xbf  = (unsigned short*)(ws);                           // 67 MB
    unsigned short* hbuf = (unsigned short*)(ws + 67108864);                // 33.5 MB
    unsigned short* w13p = (unsigned short*)(ws + 67108864 + 33554432);     // 134 MB
    unsigned short* w2p  = (unsigned short*)(ws + 67108864 + 33554432 + 134217728); // 67 MB

    cvt_x_k  <<<dim3(16384, 1, 1), dim3(256, 1, 1), 0, stream>>>(x, xbf);
    cvt_w13_k<<<dim3(16, 16, NEXP), dim3(256, 1, 1), 0, stream>>>(w13, w13p);
    gemm1    <<<dim3(4096, 1, 1), dim3(256, 1, 1), 0, stream>>>(xbf, tpe, w13p, hbuf, w2, w2p);
    gemm2    <<<dim3(4096, 1, 1), dim3(256, 1, 1), 0, stream>>>(hbuf, tpe, w2p, out);
}